// Round 3
// baseline (96.970 us; speedup 1.0000x reference)
//
#include <hip/hip_runtime.h>

#define PNUM 512
#define LB_BLOCKS 512   // L_PREDS * BATCH = 2 * 256

// One block per (l,b). 256 threads; thread t owns shifts i0=2t, i1=2t+1.
// All LDS traffic is ds_read_b128 (the only width near LDS peak, m134):
//  - gt window: float4 = 2 points, sliding by one float4 per 2 j-steps
//  - pred:      float4 uniform broadcast per 2 j-steps
// smooth_l1(x) = t*(|x|-0.5t), t=min(|x|,1)  (4 VALU/component, abs is a src modifier)
__global__ __launch_bounds__(256)
void poly_match_kernel(const float* __restrict__ pred,   // (2,256,512,2)
                       const float* __restrict__ gt,     // (256,512,2)
                       float* __restrict__ block_min)    // (512,)
{
    __shared__ float4 sp4[PNUM / 2];    // pred: 256 float4 = 512 points (4 KB)
    __shared__ float4 sg4[PNUM];        // gt doubled: 512 float4 = 1024 points (8 KB)
    __shared__ float swave[4];

    const int bid = blockIdx.x;         // l*256 + b
    const int b   = bid & 255;
    const int t   = threadIdx.x;        // 0..255

    const float4* pp4 = (const float4*)(pred + (size_t)bid * PNUM * 2);
    const float4* gp4 = (const float4*)(gt   + (size_t)b   * PNUM * 2);

    float4 gv = gp4[t];
    sp4[t]        = pp4[t];
    sg4[t]        = gv;
    sg4[t + 256]  = gv;
    __syncthreads();

    float acc0 = 0.0f, acc1 = 0.0f;

    // window W0 = points {2t+j, 2t+j+1} at j=0
    float4 W0 = sg4[t];

    #pragma unroll 8
    for (int jj = 0; jj < 256; ++jj) {
        const float4 P  = sp4[jj];           // p[2jj], p[2jj+1]  (wave-uniform b128)
        const float4 W1 = sg4[t + jj + 1];   // points 2t+2jj+2, 2t+2jj+3 (b128 gather)

        // shift i0=2t:  j=2jj -> (P.xy vs W0.xy),  j=2jj+1 -> (P.zw vs W0.zw)
        // shift i1=2t+1:j=2jj -> (P.xy vs W0.zw),  j=2jj+1 -> (P.zw vs W1.xy)
        {
            float dx = P.x - W0.x, dy = P.y - W0.y;
            float tx = fminf(fabsf(dx), 1.0f), ty = fminf(fabsf(dy), 1.0f);
            acc0 = fmaf(tx, fmaf(-0.5f, tx, fabsf(dx)), acc0);
            acc0 = fmaf(ty, fmaf(-0.5f, ty, fabsf(dy)), acc0);
        }
        {
            float dx = P.z - W0.z, dy = P.w - W0.w;
            float tx = fminf(fabsf(dx), 1.0f), ty = fminf(fabsf(dy), 1.0f);
            acc0 = fmaf(tx, fmaf(-0.5f, tx, fabsf(dx)), acc0);
            acc0 = fmaf(ty, fmaf(-0.5f, ty, fabsf(dy)), acc0);
        }
        {
            float dx = P.x - W0.z, dy = P.y - W0.w;
            float tx = fminf(fabsf(dx), 1.0f), ty = fminf(fabsf(dy), 1.0f);
            acc1 = fmaf(tx, fmaf(-0.5f, tx, fabsf(dx)), acc1);
            acc1 = fmaf(ty, fmaf(-0.5f, ty, fabsf(dy)), acc1);
        }
        {
            float dx = P.z - W1.x, dy = P.w - W1.y;
            float tx = fminf(fabsf(dx), 1.0f), ty = fminf(fabsf(dy), 1.0f);
            acc1 = fmaf(tx, fmaf(-0.5f, tx, fabsf(dx)), acc1);
            acc1 = fmaf(ty, fmaf(-0.5f, ty, fabsf(dy)), acc1);
        }

        W0 = W1;
    }

    // block min: wave64 shuffle, then 4 wave leaders via LDS
    float m = fminf(acc0, acc1);
    #pragma unroll
    for (int d = 1; d < 64; d <<= 1)
        m = fminf(m, __shfl_xor(m, d, 64));

    if ((t & 63) == 0) swave[t >> 6] = m;
    __syncthreads();
    if (t == 0) {
        float mm = fminf(fminf(swave[0], swave[1]), fminf(swave[2], swave[3]));
        block_min[bid] = mm;
    }
}

// loss = sum(block_min) / (512 * 512)
__global__ __launch_bounds__(512)
void poly_match_finalize(const float* __restrict__ block_min,
                         float* __restrict__ out)
{
    const int t = threadIdx.x;
    float v = block_min[t];
    #pragma unroll
    for (int d = 1; d < 64; d <<= 1)
        v += __shfl_xor(v, d, 64);

    __shared__ float s[8];
    if ((t & 63) == 0) s[t >> 6] = v;
    __syncthreads();
    if (t == 0) {
        float tot = 0.0f;
        #pragma unroll
        for (int k = 0; k < 8; ++k) tot += s[k];
        out[0] = tot * (1.0f / (512.0f * 512.0f));
    }
}

extern "C" void kernel_launch(void* const* d_in, const int* in_sizes, int n_in,
                              void* d_out, int out_size, void* d_ws, size_t ws_size,
                              hipStream_t stream)
{
    const float* pred = (const float*)d_in[0];  // (2,256,512,2) fp32
    const float* gt   = (const float*)d_in[1];  // (256,512,2)   fp32
    float* out  = (float*)d_out;                // scalar fp32
    float* bmin = (float*)d_ws;                 // 512 floats of scratch

    poly_match_kernel<<<LB_BLOCKS, 256, 0, stream>>>(pred, gt, bmin);
    poly_match_finalize<<<1, PNUM, 0, stream>>>(bmin, out);
}

// Round 4
// 86.859 us; speedup vs baseline: 1.1164x; 1.1164x over previous
//
#include <hip/hip_runtime.h>

#define PNUM 512
#define LB_BLOCKS 512   // L_PREDS * BATCH = 2 * 256

// One block per (l,b). 256 threads; thread t owns shifts i0=2t, i1=2t+1.
// All LDS traffic is ds_read_b128. Explicit 1-iteration software prefetch
// (rotating register windows) + __launch_bounds__(256,2) for VGPR headroom —
// round-3 post-mortem showed VGPR=20 forced a serial load-wait-compute loop.
__global__ __launch_bounds__(256, 2)
void poly_match_kernel(const float* __restrict__ pred,   // (2,256,512,2)
                       const float* __restrict__ gt,     // (256,512,2)
                       float* __restrict__ block_min)    // (512,)
{
    __shared__ float4 sp4[PNUM / 2 + 1];   // pred: 256 float4 = 512 points (+1 pad for prefetch)
    __shared__ float4 sg4[PNUM + 2];       // gt doubled: 512 float4 = 1024 points (+2 pad)
    __shared__ float swave[4];

    const int bid = blockIdx.x;         // l*256 + b
    const int b   = bid & 255;
    const int t   = threadIdx.x;        // 0..255

    const float4* pp4 = (const float4*)(pred + (size_t)bid * PNUM * 2);
    const float4* gp4 = (const float4*)(gt   + (size_t)b   * PNUM * 2);

    float4 gv = gp4[t];
    sp4[t]        = pp4[t];
    sg4[t]        = gv;
    sg4[t + 256]  = gv;
    if (t < 2) {                        // pad so prefetch lookahead stays in-bounds
        sg4[512 + t] = sg4[t];          // note: writes own earlier store, same thread? no:
    }
    if (t == 0) sp4[256] = make_float4(0.f, 0.f, 0.f, 0.f);
    __syncthreads();
    // fix pad after sync (sg4[0..1] written by threads 0..1 before sync; re-write cleanly)
    if (t < 2) sg4[512 + t] = sg4[t];
    __syncthreads();

    // 4 split accumulators to shorten fma dependency chains
    float a0a = 0.0f, a0b = 0.0f, a1a = 0.0f, a1b = 0.0f;

    // register windows: Wcur = points {2t+2jj, 2t+2jj+1}, Wnext = next float4
    float4 Wcur  = sg4[t];
    float4 Wnext = sg4[t + 1];
    float4 Pcur  = sp4[0];

    #pragma unroll 8
    for (int jj = 0; jj < 256; ++jj) {
        // prefetch for iteration jj+1 (pads make max index 512/256 legal)
        const float4 Wnn = sg4[t + jj + 2];
        const float4 Pn  = sp4[jj + 1];

        // shift i0=2t:   j=2jj -> (Pcur.xy vs Wcur.xy), j=2jj+1 -> (Pcur.zw vs Wcur.zw)
        // shift i1=2t+1: j=2jj -> (Pcur.xy vs Wcur.zw), j=2jj+1 -> (Pcur.zw vs Wnext.xy)
        {
            float dx = Pcur.x - Wcur.x, dy = Pcur.y - Wcur.y;
            float tx = fminf(fabsf(dx), 1.0f), ty = fminf(fabsf(dy), 1.0f);
            a0a = fmaf(tx, fmaf(-0.5f, tx, fabsf(dx)), a0a);
            a0b = fmaf(ty, fmaf(-0.5f, ty, fabsf(dy)), a0b);
        }
        {
            float dx = Pcur.z - Wcur.z, dy = Pcur.w - Wcur.w;
            float tx = fminf(fabsf(dx), 1.0f), ty = fminf(fabsf(dy), 1.0f);
            a0a = fmaf(tx, fmaf(-0.5f, tx, fabsf(dx)), a0a);
            a0b = fmaf(ty, fmaf(-0.5f, ty, fabsf(dy)), a0b);
        }
        {
            float dx = Pcur.x - Wcur.z, dy = Pcur.y - Wcur.w;
            float tx = fminf(fabsf(dx), 1.0f), ty = fminf(fabsf(dy), 1.0f);
            a1a = fmaf(tx, fmaf(-0.5f, tx, fabsf(dx)), a1a);
            a1b = fmaf(ty, fmaf(-0.5f, ty, fabsf(dy)), a1b);
        }
        {
            float dx = Pcur.z - Wnext.x, dy = Pcur.w - Wnext.y;
            float tx = fminf(fabsf(dx), 1.0f), ty = fminf(fabsf(dy), 1.0f);
            a1a = fmaf(tx, fmaf(-0.5f, tx, fabsf(dx)), a1a);
            a1b = fmaf(ty, fmaf(-0.5f, ty, fabsf(dy)), a1b);
        }

        Wcur  = Wnext;
        Wnext = Wnn;
        Pcur  = Pn;
    }

    // block min: wave64 shuffle, then 4 wave leaders via LDS
    float m = fminf(a0a + a0b, a1a + a1b);
    #pragma unroll
    for (int d = 1; d < 64; d <<= 1)
        m = fminf(m, __shfl_xor(m, d, 64));

    if ((t & 63) == 0) swave[t >> 6] = m;
    __syncthreads();
    if (t == 0) {
        float mm = fminf(fminf(swave[0], swave[1]), fminf(swave[2], swave[3]));
        block_min[bid] = mm;
    }
}

// loss = sum(block_min) / (512 * 512)
__global__ __launch_bounds__(512)
void poly_match_finalize(const float* __restrict__ block_min,
                         float* __restrict__ out)
{
    const int t = threadIdx.x;
    float v = block_min[t];
    #pragma unroll
    for (int d = 1; d < 64; d <<= 1)
        v += __shfl_xor(v, d, 64);

    __shared__ float s[8];
    if ((t & 63) == 0) s[t >> 6] = v;
    __syncthreads();
    if (t == 0) {
        float tot = 0.0f;
        #pragma unroll
        for (int k = 0; k < 8; ++k) tot += s[k];
        out[0] = tot * (1.0f / (512.0f * 512.0f));
    }
}

extern "C" void kernel_launch(void* const* d_in, const int* in_sizes, int n_in,
                              void* d_out, int out_size, void* d_ws, size_t ws_size,
                              hipStream_t stream)
{
    const float* pred = (const float*)d_in[0];  // (2,256,512,2) fp32
    const float* gt   = (const float*)d_in[1];  // (256,512,2)   fp32
    float* out  = (float*)d_out;                // scalar fp32
    float* bmin = (float*)d_ws;                 // 512 floats of scratch

    poly_match_kernel<<<LB_BLOCKS, 256, 0, stream>>>(pred, gt, bmin);
    poly_match_finalize<<<1, PNUM, 0, stream>>>(bmin, out);
}